// Round 8
// baseline (724.750 us; speedup 1.0000x reference)
//
#include <hip/hip_runtime.h>

#define NB 8192
#define NT 1024

typedef float v4f __attribute__((ext_vector_type(4)));
typedef float v2f __attribute__((ext_vector_type(2)));

__device__ __forceinline__ float rcpf(float x) { return __builtin_amdgcn_rcpf(x); }
__device__ __forceinline__ float bperm(int addr, float v) {
    return __int_as_float(__builtin_amdgcn_ds_bpermute(addr, __float_as_int(v)));
}

#define LOG2E 1.4426950408889634f

// Mapping B: 30 lanes per batch row; lane owns ONE gate-row R = g3*10+j
// (g3: 0=r,1=z,2=n; j = hidden index) for BOTH layers. 2 rows/wave
// (lanes 60-63 idle), 4096 waves = exactly 4/SIMD, 1024 blocks = 4/CU.
// Weights/lane = 34 floats -> fully register-resident (the structural fix
// for mapping A's reload fat: 93 floats/lane never fit).
// Nonlinearity is uniform code: val = A + B*rcp(1+exp2(M*x)), per-lane A,B,M
// select sigmoid (r,z) or tanh (n). Pass 1 -> r,z; pass 2 (after bperm of
// r_hat) -> n. h broadcast via 1 ds_write + b128/b128/b64 reads per layer.
__attribute__((amdgpu_waves_per_eu(4, 4)))
__global__ __launch_bounds__(256) void gru_fused(
    const float* __restrict__ X,
    const float* __restrict__ Wih0, const float* __restrict__ Whh0,
    const float* __restrict__ bih0, const float* __restrict__ bhh0,
    const float* __restrict__ Wih1, const float* __restrict__ Whh1,
    const float* __restrict__ bih1, const float* __restrict__ bhh1,
    const float* __restrict__ Wfc,  const float* __restrict__ bfc,
    float* __restrict__ out)
{
    // [wave(4)][grp(3)][layer(2)][20 floats]; grp stride 40 floats -> write ops
    // <=2-way bank aliasing (free), read ops fully disjoint banks (hand-checked).
    __shared__ __align__(16) float hls[480];

    const int tid  = threadIdx.x;
    const int lane = tid & 63;
    const int wv   = tid >> 6;
    int g = lane / 30;               // 0,1 real rows; 2 = idle lanes 60-63
    const int l30 = lane - g * 30;   // 0..29 (idle: 0..3)
    const bool rowok = (g < 2);
    const int R  = l30;              // gate-row 0..29
    const int j  = R % 10;           // hidden index
    const int g3 = R / 10;           // 0=r 1=z 2=n
    const bool is_n = (g3 == 2);

    const int b = blockIdx.x * 8 + wv * 2 + (rowok ? g : 0);

    // ---- per-lane weights (34 floats) ----
    const float wx0 = Wih0[R * 2], wx1 = Wih0[R * 2 + 1];
    float wh[10], u1[10], v1[10];
#pragma unroll
    for (int k = 0; k < 10; ++k) {
        wh[k] = Whh0[R * 10 + k];   // layer0 W_hh row
        u1[k] = Wih1[R * 10 + k];   // layer1 W_ih row
        v1[k] = Whh1[R * 10 + k];   // layer1 W_hh row
    }
    const float bx0 = bih0[R], bh0 = bhh0[R];
    const float bx1 = bih1[R], bh1 = bhh1[R];

    // nonlinearity constants: sigm: M=-log2e, A=0, B=1 ; tanh: M=2log2e, A=1, B=-2
    const float Mc = is_n ? (2.0f * LOG2E) : (-LOG2E);
    const float Ac = is_n ? 1.0f : 0.0f;
    const float Bc = is_n ? -2.0f : 1.0f;

    // ---- LDS addressing (float indices) ----
    const int gbase = wv * 120 + (rowok ? g : 2) * 40;  // idle -> own region
    const int wslot = is_n ? j : 14;                     // non-n lanes -> scratch
    float* const L0 = hls + gbase;        // layer0 region (20 floats)
    float* const L1 = hls + gbase + 20;   // layer1 region

    // bperm source byte addrs (idle lanes mirror group 0: harmless)
    const int lb  = (rowok ? g : 0) * 30;
    const int adR = (lb + j) * 4;         // lane holding r-row j
    const int adZ = (lb + 10 + j) * 4;    // lane holding z-row j

    // zero-init this wave's LDS region (wave-private; no barrier needed)
    for (int i = lane; i < 120; i += 64) hls[wv * 120 + i] = 0.0f;

    // ---- state ----
    float h0r[10], h1r[10];
#pragma unroll
    for (int k = 0; k < 10; ++k) { h0r[k] = 0.0f; h1r[k] = 0.0f; }
    float myh0 = 0.0f, myh1 = 0.0f;

    const float2* xp = reinterpret_cast<const float2*>(X) + (size_t)b * NT;
    float2 xc = xp[0];

    for (int t = 0; t < NT; ++t) {
        const float2 xnext = xp[(t + 1 < NT) ? (t + 1) : (NT - 1)];

        // ================= layer 0 =================
        float aX = fmaf(wx1, xc.y, fmaf(wx0, xc.x, bx0));
        float aH = bh0;
#pragma unroll
        for (int k = 0; k < 10; ++k) aH = fmaf(wh[k], h0r[k], aH);
        // pass 1: r,z lanes get final sigmoid; n lanes garbage (finite)
        const float p0   = aX + aH;
        const float val  = fmaf(Bc, rcpf(1.0f + exp2f(Mc * p0)), Ac);
        const float rv   = bperm(adR, val);           // r_hat for n lanes
        const float mr   = is_n ? rv : 1.0f;
        const float q0   = fmaf(mr, aH, aX);          // n: xn + r*(hn); r,z: same as p0
        const float val2 = fmaf(Bc, rcpf(1.0f + exp2f(Mc * q0)), Ac);
        const float zv   = bperm(adZ, val);           // z_hat
        const float hn0  = fmaf(zv, myh0 - val2, val2);  // n + z*(h-n)
        myh0 = hn0;
        L0[wslot] = hn0;                              // n lanes -> slot j
        {
            const v4f a = *reinterpret_cast<const v4f*>(L0);
            const v4f c = *reinterpret_cast<const v4f*>(L0 + 4);
            const v2f e = *reinterpret_cast<const v2f*>(L0 + 8);
            h0r[0] = a.x; h0r[1] = a.y; h0r[2] = a.z; h0r[3] = a.w;
            h0r[4] = c.x; h0r[5] = c.y; h0r[6] = c.z; h0r[7] = c.w;
            h0r[8] = e.x; h0r[9] = e.y;
        }

        // ================= layer 1 (input = h0 at this t) =================
        float aX1 = bx1;
        float aH1 = bh1;
#pragma unroll
        for (int k = 0; k < 10; ++k) {
            aX1 = fmaf(u1[k], h0r[k], aX1);
            aH1 = fmaf(v1[k], h1r[k], aH1);
        }
        const float p1   = aX1 + aH1;
        const float valb = fmaf(Bc, rcpf(1.0f + exp2f(Mc * p1)), Ac);
        const float rv1  = bperm(adR, valb);
        const float mr1  = is_n ? rv1 : 1.0f;
        const float q1   = fmaf(mr1, aH1, aX1);
        const float val3 = fmaf(Bc, rcpf(1.0f + exp2f(Mc * q1)), Ac);
        const float zv1  = bperm(adZ, valb);
        const float hn1  = fmaf(zv1, myh1 - val3, val3);
        myh1 = hn1;
        L1[wslot] = hn1;
        {
            const v4f a = *reinterpret_cast<const v4f*>(L1);
            const v4f c = *reinterpret_cast<const v4f*>(L1 + 4);
            const v2f e = *reinterpret_cast<const v2f*>(L1 + 8);
            h1r[0] = a.x; h1r[1] = a.y; h1r[2] = a.z; h1r[3] = a.w;
            h1r[4] = c.x; h1r[5] = c.y; h1r[6] = c.z; h1r[7] = c.w;
            h1r[8] = e.x; h1r[9] = e.y;
        }

        xc = xnext;
    }

    // ---- FC head: out[b,o], o=0,1 on lanes l30=0,1 (weights loaded post-loop) ----
    if (rowok && l30 < 2) {
        float acc = bfc[l30];
#pragma unroll
        for (int k = 0; k < 10; ++k) acc = fmaf(Wfc[l30 * 10 + k], h1r[k], acc);
        out[(size_t)b * 2 + l30] = acc;
    }
}

extern "C" void kernel_launch(void* const* d_in, const int* in_sizes, int n_in,
                              void* d_out, int out_size, void* d_ws, size_t ws_size,
                              hipStream_t stream) {
    const float* X    = (const float*)d_in[0];
    const float* Wih0 = (const float*)d_in[1];
    const float* Whh0 = (const float*)d_in[2];
    const float* bih0 = (const float*)d_in[3];
    const float* bhh0 = (const float*)d_in[4];
    const float* Wih1 = (const float*)d_in[5];
    const float* Whh1 = (const float*)d_in[6];
    const float* bih1 = (const float*)d_in[7];
    const float* bhh1 = (const float*)d_in[8];
    const float* Wfc  = (const float*)d_in[9];
    const float* bfc  = (const float*)d_in[10];
    float* out = (float*)d_out;

    // 1024 blocks x 4 waves x 2 rows = 8192 rows; 4096 waves = 4/SIMD exactly
    gru_fused<<<NB / 8, 256, 0, stream>>>(X, Wih0, Whh0, bih0, bhh0,
                                          Wih1, Whh1, bih1, bhh1, Wfc, bfc, out);
}

// Round 9
// 587.277 us; speedup vs baseline: 1.2341x; 1.2341x over previous
//
#include <hip/hip_runtime.h>

#define NB 8192
#define NT 1024

typedef float v2f __attribute__((ext_vector_type(2)));
typedef float v4f __attribute__((ext_vector_type(4)));

__device__ __forceinline__ float rcpf(float x) { return __builtin_amdgcn_rcpf(x); }
__device__ __forceinline__ float sigm(float x) { return rcpf(1.0f + __expf(-x)); }
__device__ __forceinline__ float tanhx(float x) { return 1.0f - 2.0f * rcpf(__expf(2.0f * x) + 1.0f); }
__device__ __forceinline__ float hsum(v2f a) { return a.x + a.y; }

// Layer-split pipeline: wave0 = producer (layer 0 + input-side r/z dots of layer 1),
// wave1 = consumer (layer 1, one step behind). Per-wave weight set (56 / 44 floats)
// fits the allocator's budget -> kills the per-timestep reload fat seen in R1-R7.
// 2048 blocks x 2 waves = 4096 waves = 4/SIMD. Depth-2 LDS ring, 1 barrier/t.
// h broadcast via same-wave LDS write + vector readback (6-9 DS ops/t vs 13-15 bperm).
__attribute__((amdgpu_waves_per_eu(4, 4)))
__global__ __launch_bounds__(128) void gru_pipe(
    const float* __restrict__ X,
    const float* __restrict__ Wih0, const float* __restrict__ Whh0,
    const float* __restrict__ bih0, const float* __restrict__ bhh0,
    const float* __restrict__ Wih1, const float* __restrict__ Whh1,
    const float* __restrict__ bih1, const float* __restrict__ bhh1,
    const float* __restrict__ Wfc,  const float* __restrict__ bfc,
    float* __restrict__ out)
{
    // hand[slot][row(4)+dump][h0(10) | m_r(10) | m_z(10) | pad(6)]
    // row stride 36 floats = 144B (16B-aligned); bases mod 32 banks: 0,4,8,12,16
    // -> b128 readbacks hit disjoint bank quartets (hand-checked, <=3-way on m scalars).
    __shared__ __align__(16) float hand[2][5][36];
    __shared__ __align__(16) float h1b[5][12];   // consumer h1 broadcast (+dump row)

    const int tid  = threadIdx.x;
    const int lane = tid & 63;
    const int wv   = tid >> 6;       // 0 = producer, 1 = consumer
    const int g    = lane / 10;      // 0..3 real groups, 4..6 idle
    const int j    = lane - g * 10;  // 0..9 hidden index
    const bool act = (g < 4);
    const int gg   = act ? g : 4;    // writes: idle lanes -> dump row
    const int gr   = act ? g : 0;    // reads: idle lanes alias row 0 (harmless)
    const int b    = blockIdx.x * 4 + (act ? g : 0);

    const int r0 = j, r1 = j + 10, r2 = j + 20;

    // ---- unified per-role weight registers ----
    // wA*: P = Whh0 rows (j, j+10, j+20) ; C = Whh1 rows (j, j+10, j+20)
    const float* pA = (wv == 0) ? Whh0 : Whh1;
    v2f wA0[5], wA1[5], wA2[5];
#pragma unroll
    for (int k = 0; k < 5; ++k) {
        wA0[k] = *reinterpret_cast<const v2f*>(pA + r0 * 10 + 2 * k);
        wA1[k] = *reinterpret_cast<const v2f*>(pA + r1 * 10 + 2 * k);
        wA2[k] = *reinterpret_cast<const v2f*>(pA + r2 * 10 + 2 * k);
    }
    // wB0: P = Wih1 row j (r-gate) ; C = Wih1 row j+20 (n-gate)
    // wB1: P = Wih1 row j+10 (z-gate) ; C unused (aliases wB0 row)
    const int rowB0 = (wv == 0) ? r0 : r2;
    v2f wB0[5], wB1[5];
#pragma unroll
    for (int k = 0; k < 5; ++k) {
        wB0[k] = *reinterpret_cast<const v2f*>(Wih1 + rowB0 * 10 + 2 * k);
        wB1[k] = *reinterpret_cast<const v2f*>(Wih1 + r1 * 10 + 2 * k);
    }
    // wx: P only (layer-0 input weights)
    const v2f wx0 = *reinterpret_cast<const v2f*>(Wih0 + r0 * 2);
    const v2f wx1 = *reinterpret_cast<const v2f*>(Wih0 + r1 * 2);
    const v2f wx2 = *reinterpret_cast<const v2f*>(Wih0 + r2 * 2);

    // biases
    float c0, c1, c2, c3, c4, c5;
    if (wv == 0) {
        c0 = bih0[r0] + bhh0[r0];   // layer0 r
        c1 = bih0[r1] + bhh0[r1];   // layer0 z
        c2 = bih0[r2];              // layer0 n, x-side
        c3 = bhh0[r2];              // layer0 n, h-side
        c4 = bih1[r0];              // m_r bias
        c5 = bih1[r1];              // m_z bias
    } else {
        c0 = bhh1[r0];              // layer1 r, h-side
        c1 = bhh1[r1];              // layer1 z, h-side
        c2 = bih1[r2];              // layer1 n, x-side
        c3 = bhh1[r2];              // layer1 n, h-side
        c4 = 0.0f; c5 = 0.0f;
    }

    // ---- state: replicated h (P: h0, C: h1) + own element ----
    v2f hp[5];
#pragma unroll
    for (int k = 0; k < 5; ++k) hp[k] = (v2f){0.f, 0.f};
    float myh = 0.0f;

    const float2* xp = reinterpret_cast<const float2*>(X) + (size_t)b * NT;
    float2 xc;
    if (wv == 0) xc = xp[0];

    // precomputed LDS pointers
    float* const hw0 = &hand[0][gg][0];
    float* const hw1 = &hand[1][gg][0];
    const float* const hr0 = &hand[0][gr][0];
    const float* const hr1 = &hand[1][gr][0];
    float* const h1w = &h1b[gg][0];
    const float* const h1r = &h1b[gr][0];

    // consumer step body (processes handoff slot sp)
    auto cstep = [&](const float* hs) {
        const v4f A  = *reinterpret_cast<const v4f*>(hs);
        const v4f Bv = *reinterpret_cast<const v4f*>(hs + 4);
        const v2f Cc = *reinterpret_cast<const v2f*>(hs + 8);
        const v2f h0c0 = {A.x, A.y},  h0c1 = {A.z, A.w};
        const v2f h0c2 = {Bv.x, Bv.y}, h0c3 = {Bv.z, Bv.w};
        const v2f h0c4 = Cc;
        const float mr = hs[10 + j];
        const float mz = hs[20 + j];

        v2f a1r = (v2f){0.f, 0.f}, a1z = (v2f){0.f, 0.f}, a1h = (v2f){0.f, 0.f};
#pragma unroll
        for (int k = 0; k < 5; ++k) {
            a1r += wA0[k] * hp[k];
            a1z += wA1[k] * hp[k];
            a1h += wA2[k] * hp[k];
        }
        v2f a1n = wB0[0] * h0c0 + wB0[1] * h0c1;
        a1n += wB0[2] * h0c2 + wB0[3] * h0c3;
        a1n += wB0[4] * h0c4;

        const float rr = sigm(mr + c0 + hsum(a1r));
        const float zz = sigm(mz + c1 + hsum(a1z));
        const float nn = tanhx(c2 + hsum(a1n) + rr * (c3 + hsum(a1h)));
        myh = nn + zz * (myh - nn);

        h1w[j] = myh;
        const v4f D = *reinterpret_cast<const v4f*>(h1r);
        const v4f E = *reinterpret_cast<const v4f*>(h1r + 4);
        const v2f F = *reinterpret_cast<const v2f*>(h1r + 8);
        hp[0] = (v2f){D.x, D.y}; hp[1] = (v2f){D.z, D.w};
        hp[2] = (v2f){E.x, E.y}; hp[3] = (v2f){E.z, E.w};
        hp[4] = F;
    };

    for (int i = 0; i < NT; ++i) {
        if (wv == 0) {
            // -------- producer: layer 0 step t=i, plus m_rz handoff --------
            const float2 xn2 = xp[(i + 1 < NT) ? (i + 1) : (NT - 1)];
            const v2f xv = {xc.x, xc.y};
            v2f ar = wx0 * xv, az = wx1 * xv, ax = wx2 * xv;
            v2f ah = (v2f){0.f, 0.f};
#pragma unroll
            for (int k = 0; k < 5; ++k) {
                ar += wA0[k] * hp[k];
                az += wA1[k] * hp[k];
                ah += wA2[k] * hp[k];
            }
            const float r = sigm(c0 + hsum(ar));
            const float z = sigm(c1 + hsum(az));
            const float n = tanhx(c2 + hsum(ax) + r * (c3 + hsum(ah)));
            myh = n + z * (myh - n);

            float* const hw = (i & 1) ? hw1 : hw0;
            const float* const hrd = (i & 1) ? hr1 : hr0;
            hw[j] = myh;
            // readback -> replicated h0 for next step + m dots
            const v4f A  = *reinterpret_cast<const v4f*>(hrd);
            const v4f Bv = *reinterpret_cast<const v4f*>(hrd + 4);
            const v2f Cc = *reinterpret_cast<const v2f*>(hrd + 8);
            hp[0] = (v2f){A.x, A.y};  hp[1] = (v2f){A.z, A.w};
            hp[2] = (v2f){Bv.x, Bv.y}; hp[3] = (v2f){Bv.z, Bv.w};
            hp[4] = Cc;

            v2f mr = (v2f){0.f, 0.f}, mz = (v2f){0.f, 0.f};
#pragma unroll
            for (int k = 0; k < 5; ++k) {
                mr += wB0[k] * hp[k];
                mz += wB1[k] * hp[k];
            }
            hw[10 + j] = c4 + hsum(mr);
            hw[20 + j] = c5 + hsum(mz);
            xc = xn2;
        } else if (i > 0) {
            // -------- consumer: layer 1 step t=i-1 --------
            cstep(((i - 1) & 1) ? hr1 : hr0);
        }
        __syncthreads();
    }

    if (wv == 1) {
        // final consumer step: t = NT-1 (slot (NT-1)&1 = 1)
        cstep(hr1);
        // FC head
        if (act && j < 2) {
            float acc = bfc[j];
#pragma unroll
            for (int k = 0; k < 5; ++k)
                acc += Wfc[j * 10 + 2 * k] * hp[k].x + Wfc[j * 10 + 2 * k + 1] * hp[k].y;
            out[(size_t)b * 2 + j] = acc;
        }
    }
}

extern "C" void kernel_launch(void* const* d_in, const int* in_sizes, int n_in,
                              void* d_out, int out_size, void* d_ws, size_t ws_size,
                              hipStream_t stream) {
    const float* X    = (const float*)d_in[0];
    const float* Wih0 = (const float*)d_in[1];
    const float* Whh0 = (const float*)d_in[2];
    const float* bih0 = (const float*)d_in[3];
    const float* bhh0 = (const float*)d_in[4];
    const float* Wih1 = (const float*)d_in[5];
    const float* Whh1 = (const float*)d_in[6];
    const float* bih1 = (const float*)d_in[7];
    const float* bhh1 = (const float*)d_in[8];
    const float* Wfc  = (const float*)d_in[9];
    const float* bfc  = (const float*)d_in[10];
    float* out = (float*)d_out;

    // 2048 blocks x 2 waves (P+C), 4 rows each = 8192 rows; 4096 waves = 4/SIMD
    gru_pipe<<<NB / 4, 128, 0, stream>>>(X, Wih0, Whh0, bih0, bhh0,
                                         Wih1, Whh1, bih1, bhh1, Wfc, bfc, out);
}

// Round 10
// 543.891 us; speedup vs baseline: 1.3325x; 1.0798x over previous
//
#include <hip/hip_runtime.h>

#define NB 8192
#define NT 1024
#define NH 10
#define ROWS_PER_WAVE 4     // 10 lanes/row, lanes 40..63 idle
#define ROWS_PER_BLOCK 16   // 4 waves/block

typedef float v2f __attribute__((ext_vector_type(2)));
typedef float v4f __attribute__((ext_vector_type(4)));

#define LOG2E 1.44269504088896340736f

__device__ __forceinline__ float rcpf(float x) { return __builtin_amdgcn_rcpf(x); }
__device__ __forceinline__ float exp2i(float x) {   // single v_exp_f32, no libm guards
    float r;
    asm("v_exp_f32 %0, %1" : "=v"(r) : "v"(x));
    return r;
}
__device__ __forceinline__ float bperm(int addr, float v) {
    return __int_as_float(__builtin_amdgcn_ds_bpermute(addr, __float_as_int(v)));
}

// q accumulated in log2 domain with -log2e pre-scaled weights: sigm = 1/(1+2^q)
__device__ __forceinline__ float sigm2q(float q) { return rcpf(1.0f + exp2i(q)); }
// u accumulated with 2*log2e pre-scaled weights: tanh = 1 - 2/(2^u + 1)
__device__ __forceinline__ float tanh2u(float u) { return fmaf(-2.0f, rcpf(exp2i(u) + 1.0f), 1.0f); }

// Row of 10 weights as v4f/v4f/v2f (b128-shaped loads), consumed scalar-wise.
struct W10 { v4f a, b; v2f c; };
__device__ __forceinline__ W10 loadrow_scaled(const float* __restrict__ p, float s) {
    W10 w;
    w.a = (v4f){p[0] * s, p[1] * s, p[2] * s, p[3] * s};
    w.b = (v4f){p[4] * s, p[5] * s, p[6] * s, p[7] * s};
    w.c = (v2f){p[8] * s, p[9] * s};
    return w;
}
// acc += w . h   (10 scalar FMAs, serial into acc)
__device__ __forceinline__ float dotW(const W10& w, const float* h, float acc) {
    acc = fmaf(w.a.x, h[0], acc); acc = fmaf(w.a.y, h[1], acc);
    acc = fmaf(w.a.z, h[2], acc); acc = fmaf(w.a.w, h[3], acc);
    acc = fmaf(w.b.x, h[4], acc); acc = fmaf(w.b.y, h[5], acc);
    acc = fmaf(w.b.z, h[6], acc); acc = fmaf(w.b.w, h[7], acc);
    acc = fmaf(w.c.x, h[8], acc); acc = fmaf(w.c.y, h[9], acc);
    return acc;
}

__global__ __launch_bounds__(256) void gru_fused(
    const float* __restrict__ X,
    const float* __restrict__ Wih0, const float* __restrict__ Whh0,
    const float* __restrict__ bih0, const float* __restrict__ bhh0,
    const float* __restrict__ Wih1, const float* __restrict__ Whh1,
    const float* __restrict__ bih1, const float* __restrict__ bhh1,
    const float* __restrict__ Wfc,  const float* __restrict__ bfc,
    float* __restrict__ out)
{
    const int tid  = threadIdx.x;
    const int lane = tid & 63;
    const int wave = tid >> 6;
    const int g    = lane / 10;      // 0..3 real, 4..6 idle
    const int j    = lane - g * 10;  // 0..9
    const int base = g * 10;

    const bool active = (g < ROWS_PER_WAVE);
    int b = blockIdx.x * ROWS_PER_BLOCK + wave * ROWS_PER_WAVE + (active ? g : 0);
    const bool store_ok = active && (b < NB);
    if (b >= NB) b = NB - 1;

    const int r0 = j, r1 = j + 10, r2 = j + 20;
    const float Sz = -LOG2E;         // r,z rows: sigmoid in log2 domain
    const float Sn = 2.0f * LOG2E;   // n rows: tanh in log2 domain

    // ---- per-lane weights, pre-scaled into the log2 domain ----
    const float wxr0 = Wih0[r0 * 2] * Sz, wxr1 = Wih0[r0 * 2 + 1] * Sz;
    const float wxz0 = Wih0[r1 * 2] * Sz, wxz1 = Wih0[r1 * 2 + 1] * Sz;
    const float wxn0 = Wih0[r2 * 2] * Sn, wxn1 = Wih0[r2 * 2 + 1] * Sn;

    const W10 whr0 = loadrow_scaled(Whh0 + r0 * NH, Sz);
    const W10 whz0 = loadrow_scaled(Whh0 + r1 * NH, Sz);
    const W10 whn0 = loadrow_scaled(Whh0 + r2 * NH, Sn);
    const W10 wir1 = loadrow_scaled(Wih1 + r0 * NH, Sz);
    const W10 wiz1 = loadrow_scaled(Wih1 + r1 * NH, Sz);
    const W10 win1 = loadrow_scaled(Wih1 + r2 * NH, Sn);
    const W10 whr1 = loadrow_scaled(Whh1 + r0 * NH, Sz);
    const W10 whz1 = loadrow_scaled(Whh1 + r1 * NH, Sz);
    const W10 whn1 = loadrow_scaled(Whh1 + r2 * NH, Sn);

    const float br0  = (bih0[r0] + bhh0[r0]) * Sz;
    const float bz0  = (bih0[r1] + bhh0[r1]) * Sz;
    const float bxn0 = bih0[r2] * Sn;
    const float bhn0 = bhh0[r2] * Sn;
    const float br1  = (bih1[r0] + bhh1[r0]) * Sz;
    const float bz1  = (bih1[r1] + bhh1[r1]) * Sz;
    const float bxn1 = bih1[r2] * Sn;
    const float bhn1 = bhh1[r2] * Sn;

    const int ad0 = base << 2;

    float h0[NH], h1[NH];
#pragma unroll
    for (int k = 0; k < NH; ++k) { h0[k] = 0.0f; h1[k] = 0.0f; }
    float my0 = 0.0f, my1 = 0.0f;

    const float2* xp = reinterpret_cast<const float2*>(X) + (size_t)b * NT;
    float2 xc = xp[0];
    float2 xn2;

#define STEP(DO_PREFETCH, T)                                                   \
    do {                                                                       \
        if (DO_PREFETCH) xn2 = xp[(T) + 1];                                    \
        /* layer 0 */                                                          \
        float pr = fmaf(wxr1, xc.y, fmaf(wxr0, xc.x, br0));                    \
        float pz = fmaf(wxz1, xc.y, fmaf(wxz0, xc.x, bz0));                    \
        float px = fmaf(wxn1, xc.y, fmaf(wxn0, xc.x, bxn0));                   \
        pr = dotW(whr0, h0, pr);                                               \
        pz = dotW(whz0, h0, pz);                                               \
        float ph = dotW(whn0, h0, bhn0);                                       \
        const float r = sigm2q(pr);                                            \
        const float z = sigm2q(pz);                                            \
        const float n = tanh2u(fmaf(r, ph, px));                               \
        my0 = fmaf(z, my0 - n, n);                                             \
        _Pragma("unroll")                                                      \
        for (int k = 0; k < NH; ++k) h0[k] = bperm(ad0 + 4 * k, my0);          \
        /* layer 1 */                                                          \
        float qr = dotW(whr1, h1, dotW(wir1, h0, br1));                        \
        float qz = dotW(whz1, h1, dotW(wiz1, h0, bz1));                        \
        float qx = dotW(win1, h0, bxn1);                                       \
        float qh = dotW(whn1, h1, bhn1);                                       \
        const float r1v = sigm2q(qr);                                          \
        const float z1v = sigm2q(qz);                                          \
        const float n1v = tanh2u(fmaf(r1v, qh, qx));                           \
        my1 = fmaf(z1v, my1 - n1v, n1v);                                       \
        _Pragma("unroll")                                                      \
        for (int k = 0; k < NH; ++k) h1[k] = bperm(ad0 + 4 * k, my1);          \
        if (DO_PREFETCH) xc = xn2;                                             \
    } while (0)

#pragma unroll 2
    for (int t = 0; t < NT - 1; ++t) {
        STEP(true, t);
    }
    STEP(false, NT - 1);   // peeled: no prefetch, no bounds select anywhere
#undef STEP

    // ---- FC head ----
    if (store_ok && j < 2) {
        float acc = bfc[j];
#pragma unroll
        for (int k = 0; k < NH; ++k) acc = fmaf(Wfc[j * NH + k], h1[k], acc);
        out[(size_t)b * 2 + j] = acc;
    }
}

extern "C" void kernel_launch(void* const* d_in, const int* in_sizes, int n_in,
                              void* d_out, int out_size, void* d_ws, size_t ws_size,
                              hipStream_t stream) {
    const float* X    = (const float*)d_in[0];
    const float* Wih0 = (const float*)d_in[1];
    const float* Whh0 = (const float*)d_in[2];
    const float* bih0 = (const float*)d_in[3];
    const float* bhh0 = (const float*)d_in[4];
    const float* Wih1 = (const float*)d_in[5];
    const float* Whh1 = (const float*)d_in[6];
    const float* bih1 = (const float*)d_in[7];
    const float* bhh1 = (const float*)d_in[8];
    const float* Wfc  = (const float*)d_in[9];
    const float* bfc  = (const float*)d_in[10];
    float* out = (float*)d_out;

    const int grid = NB / ROWS_PER_BLOCK;  // 512 blocks -> 2048 waves = 2/SIMD
    gru_fused<<<grid, 256, 0, stream>>>(X, Wih0, Whh0, bih0, bhh0,
                                        Wih1, Whh1, bih1, bhh1, Wfc, bfc, out);
}

// Round 11
// 526.462 us; speedup vs baseline: 1.3766x; 1.0331x over previous
//
#include <hip/hip_runtime.h>

#define NB 8192
#define NT 1024
#define NH 10
#define ROWS_PER_WAVE 4     // 10 lanes/row, lanes 40..63 idle
#define ROWS_PER_BLOCK 16   // 4 waves/block

typedef float v2f __attribute__((ext_vector_type(2)));
typedef float v4f __attribute__((ext_vector_type(4)));

#define LOG2E 1.44269504088896340736f

__device__ __forceinline__ float rcpf(float x) { return __builtin_amdgcn_rcpf(x); }
__device__ __forceinline__ float exp2i(float x) {   // single v_exp_f32, no libm guards
    float r;
    asm("v_exp_f32 %0, %1" : "=v"(r) : "v"(x));
    return r;
}

// q accumulated in log2 domain with -log2e pre-scaled weights: sigm = 1/(1+2^q)
__device__ __forceinline__ float sigm2q(float q) { return rcpf(1.0f + exp2i(q)); }
// u accumulated with 2*log2e pre-scaled weights: tanh = 1 - 2/(2^u + 1)
__device__ __forceinline__ float tanh2u(float u) { return fmaf(-2.0f, rcpf(exp2i(u) + 1.0f), 1.0f); }

// Row of 10 weights as v4f/v4f/v2f (b128-shaped loads), consumed element-wise.
struct W10 { v4f a, b; v2f c; };
__device__ __forceinline__ W10 loadrow_scaled(const float* __restrict__ p, float s) {
    W10 w;
    w.a = (v4f){p[0] * s, p[1] * s, p[2] * s, p[3] * s};
    w.b = (v4f){p[4] * s, p[5] * s, p[6] * s, p[7] * s};
    w.c = (v2f){p[8] * s, p[9] * s};
    return w;
}
// acc += w . h  (h as v4f/v4f/v2f register tuple, element access = plain regs)
__device__ __forceinline__ float dotW(const W10& w, v4f ha, v4f hb, v2f hc, float acc) {
    acc = fmaf(w.a.x, ha.x, acc); acc = fmaf(w.a.y, ha.y, acc);
    acc = fmaf(w.a.z, ha.z, acc); acc = fmaf(w.a.w, ha.w, acc);
    acc = fmaf(w.b.x, hb.x, acc); acc = fmaf(w.b.y, hb.y, acc);
    acc = fmaf(w.b.z, hb.z, acc); acc = fmaf(w.b.w, hb.w, acc);
    acc = fmaf(w.c.x, hc.x, acc); acc = fmaf(w.c.y, hc.y, acc);
    return acc;
}

__global__ __launch_bounds__(256) void gru_fused(
    const float* __restrict__ X,
    const float* __restrict__ Wih0, const float* __restrict__ Whh0,
    const float* __restrict__ bih0, const float* __restrict__ bhh0,
    const float* __restrict__ Wih1, const float* __restrict__ Whh1,
    const float* __restrict__ bih1, const float* __restrict__ bhh1,
    const float* __restrict__ Wfc,  const float* __restrict__ bfc,
    float* __restrict__ out)
{
    // Broadcast buffer. Group stride 12 floats (48 B, 16B-aligned).
    // Writes (lane j -> word g*12+j): banks <=2-way aliased (free, m136).
    // Reads: b128 bases {0,12,24,36,48} words -> banks {0-3,12-15,24-27,4-7,16-19}
    // disjoint; +16B and +32B sets also disjoint (hand-checked). Same-address
    // reads within a group broadcast. Wave-private region -> no barriers.
    __shared__ __align__(16) float hls[4][2][5][12];

    const int tid  = threadIdx.x;
    const int lane = tid & 63;
    const int wave = tid >> 6;
    const int g    = lane / 10;      // 0..3 real, 4..6 idle
    const int j    = lane - g * 10;  // 0..9
    const int gg   = (g < 4) ? g : 4;  // idle lanes use dump row 4

    const bool active = (g < ROWS_PER_WAVE);
    int b = blockIdx.x * ROWS_PER_BLOCK + wave * ROWS_PER_WAVE + (active ? g : 0);
    const bool store_ok = active && (b < NB);
    if (b >= NB) b = NB - 1;

    const int r0 = j, r1 = j + 10, r2 = j + 20;
    const float Sz = -LOG2E;         // r,z rows: sigmoid in log2 domain
    const float Sn = 2.0f * LOG2E;   // n rows: tanh in log2 domain

    // ---- per-lane weights, pre-scaled into the log2 domain ----
    const float wxr0 = Wih0[r0 * 2] * Sz, wxr1 = Wih0[r0 * 2 + 1] * Sz;
    const float wxz0 = Wih0[r1 * 2] * Sz, wxz1 = Wih0[r1 * 2 + 1] * Sz;
    const float wxn0 = Wih0[r2 * 2] * Sn, wxn1 = Wih0[r2 * 2 + 1] * Sn;

    const W10 whr0 = loadrow_scaled(Whh0 + r0 * NH, Sz);
    const W10 whz0 = loadrow_scaled(Whh0 + r1 * NH, Sz);
    const W10 whn0 = loadrow_scaled(Whh0 + r2 * NH, Sn);
    const W10 wir1 = loadrow_scaled(Wih1 + r0 * NH, Sz);
    const W10 wiz1 = loadrow_scaled(Wih1 + r1 * NH, Sz);
    const W10 win1 = loadrow_scaled(Wih1 + r2 * NH, Sn);
    const W10 whr1 = loadrow_scaled(Whh1 + r0 * NH, Sz);
    const W10 whz1 = loadrow_scaled(Whh1 + r1 * NH, Sz);
    const W10 whn1 = loadrow_scaled(Whh1 + r2 * NH, Sn);

    const float br0  = (bih0[r0] + bhh0[r0]) * Sz;
    const float bz0  = (bih0[r1] + bhh0[r1]) * Sz;
    const float bxn0 = bih0[r2] * Sn;
    const float bhn0 = bhh0[r2] * Sn;
    const float br1  = (bih1[r0] + bhh1[r0]) * Sz;
    const float bz1  = (bih1[r1] + bhh1[r1]) * Sz;
    const float bxn1 = bih1[r2] * Sn;
    const float bhn1 = bhh1[r2] * Sn;

    float* const L0 = &hls[wave][0][gg][0];
    float* const L1 = &hls[wave][1][gg][0];

    // replicated h state in register tuples (zero initial state)
    v4f h0a = (v4f){0,0,0,0}, h0b = (v4f){0,0,0,0}; v2f h0c = (v2f){0,0};
    v4f h1a = (v4f){0,0,0,0}, h1b = (v4f){0,0,0,0}; v2f h1c = (v2f){0,0};
    float my0 = 0.0f, my1 = 0.0f;

    const float2* xp = reinterpret_cast<const float2*>(X) + (size_t)b * NT;
    float2 xc = xp[0];
    float2 xn2;

#define STEP(DO_PREFETCH, T)                                                    \
    do {                                                                        \
        if (DO_PREFETCH) xn2 = xp[(T) + 1];                                     \
        /* ---------- layer 0 ---------- */                                     \
        float pr = fmaf(wxr1, xc.y, fmaf(wxr0, xc.x, br0));                     \
        float pz = fmaf(wxz1, xc.y, fmaf(wxz0, xc.x, bz0));                     \
        float px = fmaf(wxn1, xc.y, fmaf(wxn0, xc.x, bxn0));                    \
        pr = dotW(whr0, h0a, h0b, h0c, pr);                                     \
        pz = dotW(whz0, h0a, h0b, h0c, pz);                                     \
        const float ph = dotW(whn0, h0a, h0b, h0c, bhn0);                       \
        const float r = sigm2q(pr);                                             \
        const float z = sigm2q(pz);                                             \
        const float n = tanh2u(fmaf(r, ph, px));                                \
        my0 = fmaf(z, my0 - n, n);                                              \
        L0[j] = my0;                                                            \
        h0a = *reinterpret_cast<const v4f*>(L0);                                \
        h0b = *reinterpret_cast<const v4f*>(L0 + 4);                            \
        h0c = *reinterpret_cast<const v2f*>(L0 + 8);                            \
        /* ---------- layer 1 (split chains: two 10-FMA dots + add) ----- */    \
        const float qra = dotW(wir1, h0a, h0b, h0c, br1);                       \
        const float qrb = dotW(whr1, h1a, h1b, h1c, 0.0f);                      \
        const float qza = dotW(wiz1, h0a, h0b, h0c, bz1);                       \
        const float qzb = dotW(whz1, h1a, h1b, h1c, 0.0f);                      \
        const float qx  = dotW(win1, h0a, h0b, h0c, bxn1);                      \
        const float qh  = dotW(whn1, h1a, h1b, h1c, bhn1);                      \
        const float r1v = sigm2q(qra + qrb);                                    \
        const float z1v = sigm2q(qza + qzb);                                    \
        const float n1v = tanh2u(fmaf(r1v, qh, qx));                            \
        my1 = fmaf(z1v, my1 - n1v, n1v);                                        \
        L1[j] = my1;                                                            \
        h1a = *reinterpret_cast<const v4f*>(L1);                                \
        h1b = *reinterpret_cast<const v4f*>(L1 + 4);                            \
        h1c = *reinterpret_cast<const v2f*>(L1 + 8);                            \
        if (DO_PREFETCH) xc = xn2;                                              \
    } while (0)

    for (int t = 0; t < NT - 1; ++t) {
        STEP(true, t);
    }
    STEP(false, NT - 1);   // peeled: no prefetch, no bounds select anywhere
#undef STEP

    // ---- FC head ----
    if (store_ok && j < 2) {
        float acc = bfc[j];
        const W10 wf = loadrow_scaled(Wfc + j * NH, 1.0f);
        acc = dotW(wf, h1a, h1b, h1c, acc);
        out[(size_t)b * 2 + j] = acc;
    }
}

extern "C" void kernel_launch(void* const* d_in, const int* in_sizes, int n_in,
                              void* d_out, int out_size, void* d_ws, size_t ws_size,
                              hipStream_t stream) {
    const float* X    = (const float*)d_in[0];
    const float* Wih0 = (const float*)d_in[1];
    const float* Whh0 = (const float*)d_in[2];
    const float* bih0 = (const float*)d_in[3];
    const float* bhh0 = (const float*)d_in[4];
    const float* Wih1 = (const float*)d_in[5];
    const float* Whh1 = (const float*)d_in[6];
    const float* bih1 = (const float*)d_in[7];
    const float* bhh1 = (const float*)d_in[8];
    const float* Wfc  = (const float*)d_in[9];
    const float* bfc  = (const float*)d_in[10];
    float* out = (float*)d_out;

    const int grid = NB / ROWS_PER_BLOCK;  // 512 blocks -> 2048 waves = 2/SIMD
    gru_fused<<<grid, 256, 0, stream>>>(X, Wih0, Whh0, bih0, bhh0,
                                        Wih1, Whh1, bih1, bhh1, Wfc, bfc, out);
}

// Round 12
// 454.521 us; speedup vs baseline: 1.5945x; 1.1583x over previous
//
#include <hip/hip_runtime.h>

#define NB 8192
#define NT 1024
#define NH 10
#define ROWS_PER_WAVE 4     // 10 lanes/row, lanes 40..63 idle
#define ROWS_PER_BLOCK 16   // 4 waves/block

typedef float v2f __attribute__((ext_vector_type(2)));
typedef float v4f __attribute__((ext_vector_type(4)));

#define LOG2E 1.44269504088896340736f

__device__ __forceinline__ float rcpf(float x) { return __builtin_amdgcn_rcpf(x); }
__device__ __forceinline__ float exp2i(float x) {   // single v_exp_f32, no libm guards
    float r;
    asm("v_exp_f32 %0, %1" : "=v"(r) : "v"(x));
    return r;
}

// q accumulated in log2 domain with -log2e pre-scaled weights: sigm = 1/(1+2^q)
__device__ __forceinline__ float sigm2q(float q) { return rcpf(1.0f + exp2i(q)); }
// u accumulated with 2*log2e pre-scaled weights: tanh = 1 - 2/(2^u + 1)
__device__ __forceinline__ float tanh2u(float u) { return fmaf(-2.0f, rcpf(exp2i(u) + 1.0f), 1.0f); }

__device__ __forceinline__ v2f lo2(v4f a) { return __builtin_shufflevector(a, a, 0, 1); }
__device__ __forceinline__ v2f hi2(v4f a) { return __builtin_shufflevector(a, a, 2, 3); }
__device__ __forceinline__ v2f pkfma(v2f a, v2f b, v2f c) {  // -> v_pk_fma_f32 (no asm)
    return __builtin_elementwise_fma(a, b, c);
}

// Row of 10 weights as 5 v2f pairs (pk_fma operands).
struct W5 { v2f p[5]; };
__device__ __forceinline__ W5 loadrow_scaled(const float* __restrict__ q, float s) {
    W5 w;
#pragma unroll
    for (int k = 0; k < 5; ++k) w.p[k] = (v2f){q[2 * k] * s, q[2 * k + 1] * s};
    return w;
}
// bias + w . h   (5 pk_fma + 1 hsum)
__device__ __forceinline__ float dotW(const W5& w, v4f ha, v4f hb, v2f hc, float bias) {
    v2f acc = (v2f){bias, 0.0f};
    acc = pkfma(w.p[0], lo2(ha), acc);
    acc = pkfma(w.p[1], hi2(ha), acc);
    acc = pkfma(w.p[2], lo2(hb), acc);
    acc = pkfma(w.p[3], hi2(hb), acc);
    acc = pkfma(w.p[4], hc, acc);
    return acc.x + acc.y;
}
// bias + wa . h  + wb . g   (10 pk_fma + 1 hsum)
__device__ __forceinline__ float dot2W(const W5& wa, v4f ha, v4f hb, v2f hc,
                                       const W5& wb, v4f ga, v4f gb, v2f gc, float bias) {
    v2f acc = (v2f){bias, 0.0f};
    acc = pkfma(wa.p[0], lo2(ha), acc);
    acc = pkfma(wa.p[1], hi2(ha), acc);
    acc = pkfma(wa.p[2], lo2(hb), acc);
    acc = pkfma(wa.p[3], hi2(hb), acc);
    acc = pkfma(wa.p[4], hc, acc);
    acc = pkfma(wb.p[0], lo2(ga), acc);
    acc = pkfma(wb.p[1], hi2(ga), acc);
    acc = pkfma(wb.p[2], lo2(gb), acc);
    acc = pkfma(wb.p[3], hi2(gb), acc);
    acc = pkfma(wb.p[4], gc, acc);
    return acc.x + acc.y;
}

__global__ __launch_bounds__(256) void gru_fused(
    const float* __restrict__ X,
    const float* __restrict__ Wih0, const float* __restrict__ Whh0,
    const float* __restrict__ bih0, const float* __restrict__ bhh0,
    const float* __restrict__ Wih1, const float* __restrict__ Whh1,
    const float* __restrict__ bih1, const float* __restrict__ bhh1,
    const float* __restrict__ Wfc,  const float* __restrict__ bfc,
    float* __restrict__ out)
{
    // Broadcast buffer (R10 layout, read-conflict-free; writes <=2-way = ~1 cyc).
    __shared__ __align__(16) float hls[4][2][5][12];

    const int tid  = threadIdx.x;
    const int lane = tid & 63;
    const int wave = tid >> 6;
    const int g    = lane / 10;      // 0..3 real, 4..6 idle
    const int j    = lane - g * 10;  // 0..9
    const int gg   = (g < 4) ? g : 4;  // idle lanes use dump row 4

    const bool active = (g < ROWS_PER_WAVE);
    int b = blockIdx.x * ROWS_PER_BLOCK + wave * ROWS_PER_WAVE + (active ? g : 0);
    const bool store_ok = active && (b < NB);
    if (b >= NB) b = NB - 1;

    const int r0 = j, r1 = j + 10, r2 = j + 20;
    const float Sz = -LOG2E;         // r,z rows: sigmoid in log2 domain
    const float Sn = 2.0f * LOG2E;   // n rows: tanh in log2 domain

    // ---- per-lane weights, pre-scaled into the log2 domain ----
    const v2f wxr = (v2f){Wih0[r0 * 2] * Sz, Wih0[r0 * 2 + 1] * Sz};
    const v2f wxz = (v2f){Wih0[r1 * 2] * Sz, Wih0[r1 * 2 + 1] * Sz};
    const v2f wxn = (v2f){Wih0[r2 * 2] * Sn, Wih0[r2 * 2 + 1] * Sn};

    const W5 whr0 = loadrow_scaled(Whh0 + r0 * NH, Sz);
    const W5 whz0 = loadrow_scaled(Whh0 + r1 * NH, Sz);
    const W5 whn0 = loadrow_scaled(Whh0 + r2 * NH, Sn);
    const W5 wir1 = loadrow_scaled(Wih1 + r0 * NH, Sz);
    const W5 wiz1 = loadrow_scaled(Wih1 + r1 * NH, Sz);
    const W5 win1 = loadrow_scaled(Wih1 + r2 * NH, Sn);
    const W5 whr1 = loadrow_scaled(Whh1 + r0 * NH, Sz);
    const W5 whz1 = loadrow_scaled(Whh1 + r1 * NH, Sz);
    const W5 whn1 = loadrow_scaled(Whh1 + r2 * NH, Sn);

    const float br0  = (bih0[r0] + bhh0[r0]) * Sz;
    const float bz0  = (bih0[r1] + bhh0[r1]) * Sz;
    const float bxn0 = bih0[r2] * Sn;
    const float bhn0 = bhh0[r2] * Sn;
    const float br1  = (bih1[r0] + bhh1[r0]) * Sz;
    const float bz1  = (bih1[r1] + bhh1[r1]) * Sz;
    const float bxn1 = bih1[r2] * Sn;
    const float bhn1 = bhh1[r2] * Sn;

    float* const L0 = &hls[wave][0][gg][0];
    float* const L1 = &hls[wave][1][gg][0];

    // replicated h state (zero initial)
    v4f h0a = (v4f){0,0,0,0}, h0b = (v4f){0,0,0,0}; v2f h0c = (v2f){0,0};
    v4f h1a = (v4f){0,0,0,0}, h1b = (v4f){0,0,0,0}; v2f h1c = (v2f){0,0};
    float my0 = 0.0f, my1 = 0.0f;

    const float2* xp = reinterpret_cast<const float2*>(X) + (size_t)b * NT;
    float2 xc = xp[0];
    float2 xn2;

#define STEP(DO_PREFETCH, T)                                                    \
    do {                                                                        \
        if (DO_PREFETCH) xn2 = xp[(T) + 1];                                     \
        const v2f xv = (v2f){xc.x, xc.y};                                       \
        /* ---------- layer 0: acc seeded by input-side pk_fma ---------- */    \
        v2f accr = pkfma(wxr, xv, (v2f){br0, 0.0f});                            \
        v2f accz = pkfma(wxz, xv, (v2f){bz0, 0.0f});                            \
        v2f accx = pkfma(wxn, xv, (v2f){bxn0, 0.0f});                           \
        accr = pkfma(whr0.p[0], lo2(h0a), accr);                                \
        accr = pkfma(whr0.p[1], hi2(h0a), accr);                                \
        accr = pkfma(whr0.p[2], lo2(h0b), accr);                                \
        accr = pkfma(whr0.p[3], hi2(h0b), accr);                                \
        accr = pkfma(whr0.p[4], h0c, accr);                                     \
        accz = pkfma(whz0.p[0], lo2(h0a), accz);                                \
        accz = pkfma(whz0.p[1], hi2(h0a), accz);                                \
        accz = pkfma(whz0.p[2], lo2(h0b), accz);                                \
        accz = pkfma(whz0.p[3], hi2(h0b), accz);                                \
        accz = pkfma(whz0.p[4], h0c, accz);                                     \
        const float ph = dotW(whn0, h0a, h0b, h0c, bhn0);                       \
        const float pr = accr.x + accr.y;                                       \
        const float pz = accz.x + accz.y;                                       \
        const float px = accx.x + accx.y;                                       \
        const float r = sigm2q(pr);                                             \
        const float z = sigm2q(pz);                                             \
        const float n = tanh2u(fmaf(r, ph, px));                                \
        my0 = fmaf(z, my0 - n, n);                                              \
        L0[j] = my0;                                                            \
        h0a = *reinterpret_cast<const v4f*>(L0);                                \
        h0b = *reinterpret_cast<const v4f*>(L0 + 4);                            \
        h0c = *reinterpret_cast<const v2f*>(L0 + 8);                            \
        /* ---------- layer 1: fused 20-element dots for r,z ---------- */      \
        const float qr = dot2W(wir1, h0a, h0b, h0c, whr1, h1a, h1b, h1c, br1);  \
        const float qz = dot2W(wiz1, h0a, h0b, h0c, whz1, h1a, h1b, h1c, bz1);  \
        const float qx = dotW(win1, h0a, h0b, h0c, bxn1);                       \
        const float qh = dotW(whn1, h1a, h1b, h1c, bhn1);                       \
        const float r1v = sigm2q(qr);                                           \
        const float z1v = sigm2q(qz);                                           \
        const float n1v = tanh2u(fmaf(r1v, qh, qx));                            \
        my1 = fmaf(z1v, my1 - n1v, n1v);                                        \
        L1[j] = my1;                                                            \
        h1a = *reinterpret_cast<const v4f*>(L1);                                \
        h1b = *reinterpret_cast<const v4f*>(L1 + 4);                            \
        h1c = *reinterpret_cast<const v2f*>(L1 + 8);                            \
        if (DO_PREFETCH) xc = xn2;                                              \
    } while (0)

    for (int t = 0; t < NT - 1; ++t) {
        STEP(true, t);
    }
    STEP(false, NT - 1);   // peeled: no prefetch, no bounds select anywhere
#undef STEP

    // ---- FC head ----
    if (store_ok && j < 2) {
        const W5 wf = loadrow_scaled(Wfc + j * NH, 1.0f);
        out[(size_t)b * 2 + j] = dotW(wf, h1a, h1b, h1c, bfc[j]);
    }
}

extern "C" void kernel_launch(void* const* d_in, const int* in_sizes, int n_in,
                              void* d_out, int out_size, void* d_ws, size_t ws_size,
                              hipStream_t stream) {
    const float* X    = (const float*)d_in[0];
    const float* Wih0 = (const float*)d_in[1];
    const float* Whh0 = (const float*)d_in[2];
    const float* bih0 = (const float*)d_in[3];
    const float* bhh0 = (const float*)d_in[4];
    const float* Wih1 = (const float*)d_in[5];
    const float* Whh1 = (const float*)d_in[6];
    const float* bih1 = (const float*)d_in[7];
    const float* bhh1 = (const float*)d_in[8];
    const float* Wfc  = (const float*)d_in[9];
    const float* bfc  = (const float*)d_in[10];
    float* out = (float*)d_out;

    const int grid = NB / ROWS_PER_BLOCK;  // 512 blocks -> 2048 waves = 2/SIMD
    gru_fused<<<grid, 256, 0, stream>>>(X, Wih0, Whh0, bih0, bhh0,
                                        Wih1, Whh1, bih1, bhh1, Wfc, bfc, out);
}